// Round 6
// baseline (2263.224 us; speedup 1.0000x reference)
//
#include <hip/hip_runtime.h>
#include <hip/hip_bf16.h>

typedef __bf16 bf16_t;
typedef __bf16 bf16x8 __attribute__((ext_vector_type(8)));
typedef float  f32x4  __attribute__((ext_vector_type(4)));

#define DEV __device__ __forceinline__

DEV void gload_lds16(const void* g, void* l) {
  __builtin_amdgcn_global_load_lds(
      (__attribute__((address_space(1))) void*)(void*)g,
      (__attribute__((address_space(3))) void*)l, 16, 0, 0);
}

#define FENCE() asm volatile("" ::: "memory")
#define BAR()   do { FENCE(); __builtin_amdgcn_s_barrier(); FENCE(); } while (0)
#define LGKM0() do { asm volatile("s_waitcnt lgkmcnt(0)" ::: "memory"); \
                     __builtin_amdgcn_sched_barrier(0); } while (0)

// ---------------- weight transpose+cast: in fp32 [K][N] -> out bf16 [N][K]
__global__ __launch_bounds__(256)
void transpose_cast(const float* __restrict__ in, bf16_t* __restrict__ out,
                    int K, int N) {
  __shared__ float tile[32][33];
  const int k0 = blockIdx.x * 32;
  const int n0 = blockIdx.y * 32;
  const int tx = threadIdx.x;      // 0..31
  const int ty = threadIdx.y;      // 0..7
#pragma unroll
  for (int i = 0; i < 32; i += 8)
    tile[ty + i][tx] = in[(long)(k0 + ty + i) * N + n0 + tx];
  __syncthreads();
#pragma unroll
  for (int i = 0; i < 32; i += 8)
    out[(long)(n0 + ty + i) * K + k0 + tx] = (bf16_t)tile[tx][ty + i];
}

// ---------------- embedding: h = wte[ids] + wpe[s]
__global__ __launch_bounds__(256)
void embed_kernel(const int* __restrict__ ids, const float* __restrict__ wte,
                  const float* __restrict__ wpe, float* __restrict__ h) {
  const int idx = blockIdx.x * 256 + threadIdx.x;   // < 8192*768
  const int col = idx % 768;
  const int row = idx / 768;
  const int s   = row & 1023;
  h[idx] = wte[(long)ids[row] * 768 + col] + wpe[s * 768 + col];
}

// ---------------- layernorm, one block (256 thr) per row of 768
template <bool BF16OUT>
__global__ __launch_bounds__(256)
void ln_kernel(const float* __restrict__ x, const float* __restrict__ g,
               const float* __restrict__ b, bf16_t* __restrict__ ob,
               float* __restrict__ of) {
  const long row = blockIdx.x;
  const float* xr = x + row * 768;
  const int t = threadIdx.x;
  float v0 = xr[t], v1 = xr[t + 256], v2 = xr[t + 512];
  float s  = v0 + v1 + v2;
  float sq = v0 * v0 + v1 * v1 + v2 * v2;
#pragma unroll
  for (int o = 32; o; o >>= 1) { s += __shfl_down(s, o); sq += __shfl_down(sq, o); }
  __shared__ float red[8];
  const int w = t >> 6;
  if ((t & 63) == 0) { red[w] = s; red[4 + w] = sq; }
  __syncthreads();
  s  = red[0] + red[1] + red[2] + red[3];
  sq = red[4] + red[5] + red[6] + red[7];
  const float mean = s * (1.f / 768.f);
  const float rs = rsqrtf(sq * (1.f / 768.f) - mean * mean + 1e-5f);
  float vv[3] = {v0, v1, v2};
#pragma unroll
  for (int i = 0; i < 3; ++i) {
    const int col = t + i * 256;
    const float o2 = (vv[i] - mean) * rs * g[col] + b[col];
    if (BF16OUT) ob[row * 768 + col] = (bf16_t)o2;
    else         of[row * 768 + col] = o2;
  }
}

// ---------------- 256x256 8-phase GEMM (m201 geometry).
// C[M][N] = A[M][K](bf16) * Bt[N][K]^T + bias. BK=64; 512 thr = 8 waves
// (2M x 4N); per-wave 128x64 out (acc[8][4] f32x4). LDS 128 KB, XOR-swizzle.
// Per K-tile, 4 phases:
//  ph1: ds_read a0(8)+b0(4); stage B1(T+1)->nxt buf; BAR; lgkm0; 16 MFMA (a0,b0); BAR
//  ph2: ds_read a1(8)+b1(4); BAR; lgkm0; 16 MFMA (a0,b1); BAR
//  ph3: stage A0(T+2)->cur; BAR; 16 MFMA (a1,b1); BAR
//  ph4: stage A1(T+2)+B0(T+2)->cur; vmcnt(6)|(0); BAR; 16 MFMA (a1,b0); BAR
// FIFO proof: at ph4's vmcnt(6) outstanding = T+1:{A0,A1,B0 (from T-1 ph3/4),
// B1 (ph1)} + T+2:{A0,A1,B0} = 14; drain to 6 completes exactly all of T+1.
// Hazards: all ds_reads of buf[cur] complete (lgkm0 pre-MFMA) a full barrier
// before any ph3/ph4 stage into buf[cur] issues.
// EPI: 0 f32 store, 1 f32 +=, 2 bf16, 3 gelu->bf16, 4 atomicAdd f32 (split-K).
template <int EPI, int NSP>
__global__ __launch_bounds__(512, 2)
void gemm256(const bf16_t* __restrict__ A, const bf16_t* __restrict__ Bt,
             const float* __restrict__ bias, float* __restrict__ Cf,
             bf16_t* __restrict__ Cb, int M, int N, int K) {
  __shared__ bf16_t As[2 * 256 * 64];   // 64 KB
  __shared__ bf16_t Bs[2 * 256 * 64];   // 64 KB
  const int tid = threadIdx.x;
  const int lane = tid & 63, w = tid >> 6;
  const int col = lane & 15, s16 = lane >> 4;
  const int wm = w >> 2, wn = w & 3;          // 2 x 4 waves
  const int nbn = N >> 8;
  const int cpx = gridDim.x >> 3;
  const int swz = (blockIdx.x & 7) * cpx + (blockIdx.x >> 3);
  const int ks = (NSP > 1) ? (swz & (NSP - 1)) : 0;
  const int t0 = swz / NSP;
  const int bm = t0 / nbn, bn = t0 % nbn;
  const int Ksub = K / NSP;
  const long kofs = (long)ks * Ksub;
  const int nt = Ksub >> 6;                   // always >= 2 here
  const long arow0 = (long)bm * 256, brow0 = (long)bn * 256;

  f32x4 acc[8][4];
#pragma unroll
  for (int i = 0; i < 8; ++i)
#pragma unroll
    for (int j = 0; j < 4; ++j) acc[i][j] = f32x4{0.f, 0.f, 0.f, 0.f};

  // stage one half-tile (128 rows x 64 k = 16 KB) = 2 gload instrs/thread
  auto stA = [&](int buf, int hf, int kb) {
#pragma unroll
    for (int i = 0; i < 2; ++i) {
      const int c = i * 512 + tid;
      const int row = c >> 3, slot = c & 7;
      gload_lds16(A + (arow0 + hf * 128 + row) * (long)K + kofs + kb +
                      ((slot ^ (row & 7)) << 3),
                  (char*)As + buf * 32768 + hf * 16384 + c * 16);
    }
  };
  auto stB = [&](int buf, int hf, int kb) {
#pragma unroll
    for (int i = 0; i < 2; ++i) {
      const int c = i * 512 + tid;
      const int row = c >> 3, slot = c & 7;
      gload_lds16(Bt + (brow0 + hf * 128 + row) * (long)K + kofs + kb +
                      ((slot ^ (row & 7)) << 3),
                  (char*)Bs + buf * 32768 + hf * 16384 + c * 16);
    }
  };
  auto rdA = [&](int buf, int m, int kss) -> bf16x8 {
    const int lr = wm * 128 + m * 16 + col;
    return *(const bf16x8*)((char*)As + buf * 32768 + lr * 128 +
                            (((kss * 4 + s16) ^ (lr & 7)) << 4));
  };
  auto rdB = [&](int buf, int n, int kss) -> bf16x8 {
    const int lr = wn * 64 + n * 16 + col;
    return *(const bf16x8*)((char*)Bs + buf * 32768 + lr * 128 +
                            (((kss * 4 + s16) ^ (lr & 7)) << 4));
  };

  // prologue: T0 all 4 halves; T1 {A0, A1, B0}; wait T0 complete.
  stA(0, 0, 0); stA(0, 1, 0); stB(0, 0, 0); stB(0, 1, 0);
  stA(1, 0, 64); stA(1, 1, 64); stB(1, 0, 64);
  asm volatile("s_waitcnt vmcnt(6)" ::: "memory");
  BAR();

  int cur = 0;
#pragma unroll 1
  for (int T = 0; T < nt; ++T) {
    const int nx = cur ^ 1;
    const int kb1 = (T + 1) << 6, kb2 = (T + 2) << 6;
    const bool s1 = (T + 1 < nt), s2 = (T + 2 < nt);
    bf16x8 a0[4][2], a1[4][2], b0[2][2], b1[2][2];

    // ---- phase 1: read a0 + b0, stage B1(T+1), MFMA (a0,b0)
#pragma unroll
    for (int m = 0; m < 4; ++m)
#pragma unroll
      for (int kk = 0; kk < 2; ++kk) a0[m][kk] = rdA(cur, m, kk);
#pragma unroll
    for (int n = 0; n < 2; ++n)
#pragma unroll
      for (int kk = 0; kk < 2; ++kk) b0[n][kk] = rdB(cur, n, kk);
    if (s1) stB(nx, 1, kb1);
    BAR();
    LGKM0();
    __builtin_amdgcn_s_setprio(1);
#pragma unroll
    for (int m = 0; m < 4; ++m)
#pragma unroll
      for (int n = 0; n < 2; ++n)
#pragma unroll
        for (int kk = 0; kk < 2; ++kk)
          acc[m][n] = __builtin_amdgcn_mfma_f32_16x16x32_bf16(
              a0[m][kk], b0[n][kk], acc[m][n], 0, 0, 0);
    __builtin_amdgcn_s_setprio(0);
    BAR();

    // ---- phase 2: read a1 + b1, MFMA (a0,b1)
#pragma unroll
    for (int m = 0; m < 4; ++m)
#pragma unroll
      for (int kk = 0; kk < 2; ++kk) a1[m][kk] = rdA(cur, 4 + m, kk);
#pragma unroll
    for (int n = 0; n < 2; ++n)
#pragma unroll
      for (int kk = 0; kk < 2; ++kk) b1[n][kk] = rdB(cur, 2 + n, kk);
    BAR();
    LGKM0();
    __builtin_amdgcn_s_setprio(1);
#pragma unroll
    for (int m = 0; m < 4; ++m)
#pragma unroll
      for (int n = 0; n < 2; ++n)
#pragma unroll
        for (int kk = 0; kk < 2; ++kk)
          acc[m][2 + n] = __builtin_amdgcn_mfma_f32_16x16x32_bf16(
              a0[m][kk], b1[n][kk], acc[m][2 + n], 0, 0, 0);
    __builtin_amdgcn_s_setprio(0);
    BAR();

    // ---- phase 3: stage A0(T+2) into cur (reads of cur done), MFMA (a1,b1)
    if (s2) stA(cur, 0, kb2);
    BAR();
    __builtin_amdgcn_s_setprio(1);
#pragma unroll
    for (int m = 0; m < 4; ++m)
#pragma unroll
      for (int n = 0; n < 2; ++n)
#pragma unroll
        for (int kk = 0; kk < 2; ++kk)
          acc[4 + m][2 + n] = __builtin_amdgcn_mfma_f32_16x16x32_bf16(
              a1[m][kk], b1[n][kk], acc[4 + m][2 + n], 0, 0, 0);
    __builtin_amdgcn_s_setprio(0);
    BAR();

    // ---- phase 4: stage A1(T+2)+B0(T+2); counted vmcnt; MFMA (a1,b0)
    if (s2) { stA(cur, 1, kb2); stB(cur, 0, kb2); }
    if (s2) asm volatile("s_waitcnt vmcnt(6)" ::: "memory");
    else    asm volatile("s_waitcnt vmcnt(0)" ::: "memory");
    BAR();
    __builtin_amdgcn_s_setprio(1);
#pragma unroll
    for (int m = 0; m < 4; ++m)
#pragma unroll
      for (int n = 0; n < 2; ++n)
#pragma unroll
        for (int kk = 0; kk < 2; ++kk)
          acc[4 + m][n] = __builtin_amdgcn_mfma_f32_16x16x32_bf16(
              a1[m][kk], b0[n][kk], acc[4 + m][n], 0, 0, 0);
    __builtin_amdgcn_s_setprio(0);
    BAR();

    cur = nx;
  }

  // epilogue
  const int rowb = bm * 256 + wm * 128 + (s16 << 2);
  const int colb = bn * 256 + wn * 64 + col;
#pragma unroll
  for (int n = 0; n < 4; ++n) {
    const int ccol = colb + n * 16;
    const float bv = (EPI == 4) ? (ks == 0 ? bias[ccol] : 0.f) : bias[ccol];
#pragma unroll
    for (int m = 0; m < 8; ++m) {
      const int row = rowb + m * 16;
#pragma unroll
      for (int r = 0; r < 4; ++r) {
        const float v = acc[m][n][r] + bv;
        const long idx = (long)(row + r) * N + ccol;
        if (EPI == 0)      Cf[idx] = v;
        else if (EPI == 1) Cf[idx] += v;
        else if (EPI == 2) Cb[idx] = (bf16_t)v;
        else if (EPI == 3) {
          const float z = 0.7978845608028654f * (v + 0.044715f * v * v * v);
          Cb[idx] = (bf16_t)(v / (1.f + __expf(-2.f * z)));
        } else {
          atomicAdd(&Cf[idx], v);
        }
      }
    }
  }
}

// ---------------- flash attention: paired q-tiles, double-buffered K/V,
// async-stage split (issue-early/write-late), one barrier per kt-iteration.
__global__ __launch_bounds__(256, 3)
void attn_kernel(const bf16_t* __restrict__ qkv, const float* __restrict__ mask,
                 bf16_t* __restrict__ out) {
  __shared__ bf16_t Kl[2][64 * 64];   // [key][dh], slot-swizzled
  __shared__ bf16_t Vt[2][64 * 64];   // [d][k],   slot-swizzled
  __shared__ bf16_t Pl[4][16 * 64];   // per-wave [q][key], slot-swizzled
  const int tid = threadIdx.x, lane = tid & 63, w = tid >> 6;
  const int col = lane & 15, s16 = lane >> 4, l7 = lane & 7;
  const int qp = blockIdx.x & 7;      // pair id: handles qt = qp and 15-qp
  const int bh = blockIdx.x >> 3;     // 0..95
  const int b = bh / 12, h = bh % 12;
  const int sw0 = (s16 ^ l7) << 4;
  const int sw1 = ((s16 + 4) ^ l7) << 4;
  char* const plw = (char*)&Pl[w][0];
  const long qkvb = (long)b * 1024 * 2304;

  auto stageK = [&](int buf, int k0) {
#pragma unroll
    for (int i = 0; i < 2; ++i) {
      const int c = i * 256 + tid;
      const int krow = c >> 3, slot = c & 7;
      gload_lds16(qkv + qkvb + (long)(k0 + krow) * 2304 + 768 + h * 64 +
                      ((slot ^ (krow & 7)) << 3),
                  (char*)&Kl[buf][0] + i * 4096 + w * 1024);
    }
  };
  auto loadV = [&](int k0, bf16x8& t0, bf16x8& t1) {
    const bf16_t* vbase = qkv + qkvb + 1536 + h * 64;
#pragma unroll
    for (int i = 0; i < 2; ++i) {
      const int c = i * 256 + tid;
      const int d = c & 63, koct = c >> 6;
      const bf16_t* vsrc = vbase + (long)(k0 + koct * 8) * 2304 + d;
      bf16x8 tv;
#pragma unroll
      for (int j = 0; j < 8; ++j) tv[j] = vsrc[(long)j * 2304];
      if (i == 0) t0 = tv; else t1 = tv;
    }
  };
  auto storeV = [&](int buf, const bf16x8& t0, const bf16x8& t1) {
#pragma unroll
    for (int i = 0; i < 2; ++i) {
      const int c = i * 256 + tid;
      const int d = c & 63, koct = c >> 6;
      *(bf16x8*)((char*)&Vt[buf][0] + d * 128 + ((koct ^ (d & 7)) << 4)) =
          (i == 0) ? t0 : t1;
    }
  };

#pragma unroll 1
  for (int pass = 0; pass < 2; ++pass) {
    const int qt = pass ? (15 - qp) : qp;
    const int qrow0 = qt * 64 + w * 16;
    const long rowQ = (long)(b * 1024 + qrow0 + col) * 2304 + h * 64;
    const bf16x8 aq0 = *(const bf16x8*)&qkv[rowQ + s16 * 8];
    const bf16x8 aq1 = *(const bf16x8*)&qkv[rowQ + 32 + s16 * 8];
    const int qb = qrow0 + s16 * 4;
    const float* mrow = mask + ((long)b * 1024 + qb) * 1024;

    auto loadM = [&](int k0, float (&m)[4][4]) {
#pragma unroll
      for (int g = 0; g < 4; ++g)
#pragma unroll
        for (int r = 0; r < 4; ++r)
          m[g][r] = mrow[(long)r * 1024 + k0 + g * 16 + col];
    };

    float m_run[4], l_run[4];
    f32x4 o_acc[4];
#pragma unroll
    for (int r = 0; r < 4; ++r) { m_run[r] = -INFINITY; l_run[r] = 0.f; }
#pragma unroll
    for (int go = 0; go < 4; ++go) o_acc[go] = f32x4{0.f, 0.f, 0.f, 0.f};

    bf16x8 tv0, tv1;
    stageK(0, 0);
    loadV(0, tv0, tv1);
    storeV(0, tv0, tv1);
    float msk[4][4];
    loadM(0, msk);
    __syncthreads();

#pragma unroll 1
    for (int kt = 0; kt <= qt; ++kt) {
      const int cur = kt & 1;
      const bool more = kt < qt;
      const int k0 = kt * 64;
      float mnx[4][4];
      if (more) {
        stageK(cur ^ 1, k0 + 64);
        loadV(k0 + 64, tv0, tv1);
        loadM(k0 + 64, mnx);
      }

      f32x4 sf[4];
      __builtin_amdgcn_s_setprio(1);
#pragma unroll
      for (int g = 0; g < 4; ++g) {
        const int rbyte = (g * 16 + col) * 128;
        bf16x8 bk0 = *(const bf16x8*)((char*)&Kl[cur][0] + rbyte + sw0);
        bf16x8 bk1 = *(const bf16x8*)((char*)&Kl[cur][0] + rbyte + sw1);
        f32x4 z = f32x4{0.f, 0.f, 0.f, 0.f};
        z = __builtin_amdgcn_mfma_f32_16x16x32_bf16(aq0, bk0, z, 0, 0, 0);
        z = __builtin_amdgcn_mfma_f32_16x16x32_bf16(aq1, bk1, z, 0, 0, 0);
        sf[g] = z;
      }
      __builtin_amdgcn_s_setprio(0);

      const bool diag = (kt == qt);
      float sv[4][4];
#pragma unroll
      for (int g = 0; g < 4; ++g)
#pragma unroll
        for (int r = 0; r < 4; ++r) {
          float s = sf[g][r] * 0.125f + msk[g][r];
          if (diag && (k0 + g * 16 + col) > (qb + r)) s = -INFINITY;
          sv[g][r] = s;
        }
#pragma unroll
      for (int r = 0; r < 4; ++r) {
        float mx = fmaxf(fmaxf(sv[0][r], sv[1][r]), fmaxf(sv[2][r], sv[3][r]));
#pragma unroll
        for (int o = 8; o; o >>= 1) mx = fmaxf(mx, __shfl_xor(mx, o));
        const float m_new = fmaxf(m_run[r], mx);
        const float f = __expf(m_run[r] - m_new);
        m_run[r] = m_new;
        float sum = 0.f;
#pragma unroll
        for (int g = 0; g < 4; ++g) {
          const float p = __expf(sv[g][r] - m_new);
          sv[g][r] = p;
          sum += p;
        }
#pragma unroll
        for (int o = 8; o; o >>= 1) sum += __shfl_xor(sum, o);
        l_run[r] = l_run[r] * f + sum;
#pragma unroll
        for (int go = 0; go < 4; ++go) o_acc[go][r] *= f;
      }

#pragma unroll
      for (int g = 0; g < 4; ++g) {
        const int ks = 2 * g + (col >> 3);
#pragma unroll
        for (int r = 0; r < 4; ++r) {
          const int qr = s16 * 4 + r;
          *(bf16_t*)(plw + qr * 128 + ((ks ^ (qr & 7)) << 4) + l7 * 2) = (bf16_t)sv[g][r];
        }
      }
      const bf16x8 pa0 = *(const bf16x8*)(plw + col * 128 + sw0);
      const bf16x8 pa1 = *(const bf16x8*)(plw + col * 128 + sw1);
      __builtin_amdgcn_s_setprio(1);
#pragma unroll
      for (int go = 0; go < 4; ++go) {
        const int dbyte = (go * 16 + col) * 128;
        bf16x8 bv0 = *(const bf16x8*)((char*)&Vt[cur][0] + dbyte + sw0);
        bf16x8 bv1 = *(const bf16x8*)((char*)&Vt[cur][0] + dbyte + sw1);
        o_acc[go] = __builtin_amdgcn_mfma_f32_16x16x32_bf16(pa0, bv0, o_acc[go], 0, 0, 0);
        o_acc[go] = __builtin_amdgcn_mfma_f32_16x16x32_bf16(pa1, bv1, o_acc[go], 0, 0, 0);
      }
      __builtin_amdgcn_s_setprio(0);

      if (more) {
        storeV(cur ^ 1, tv0, tv1);
#pragma unroll
        for (int g = 0; g < 4; ++g)
#pragma unroll
          for (int r = 0; r < 4; ++r) msk[g][r] = mnx[g][r];
      }
      __syncthreads();
    }

    float inv[4];
#pragma unroll
    for (int r = 0; r < 4; ++r) inv[r] = 1.f / l_run[r];
#pragma unroll
    for (int go = 0; go < 4; ++go)
#pragma unroll
      for (int r = 0; r < 4; ++r)
        out[(long)(b * 1024 + qb + r) * 768 + h * 64 + go * 16 + col] =
            (bf16_t)(o_acc[go][r] * inv[r]);
  }
}

// ---------------- host
extern "C" void kernel_launch(void* const* d_in, const int* in_sizes, int n_in,
                              void* d_out, int out_size, void* d_ws, size_t ws_size,
                              hipStream_t stream) {
  const int*   x_ids = (const int*)d_in[0];
  const float* mask  = (const float*)d_in[1];
  const float* wte   = (const float*)d_in[2];
  const float* wpe   = (const float*)d_in[3];
  const float* ln1_g = (const float*)d_in[4];
  const float* ln1_b = (const float*)d_in[5];
  const float* qkv_w = (const float*)d_in[6];
  const float* qkv_b = (const float*)d_in[7];
  const float* ao_w  = (const float*)d_in[8];
  const float* ao_b  = (const float*)d_in[9];
  const float* ln2_g = (const float*)d_in[10];
  const float* ln2_b = (const float*)d_in[11];
  const float* fc_w  = (const float*)d_in[12];
  const float* fc_b  = (const float*)d_in[13];
  const float* op_w  = (const float*)d_in[14];
  const float* op_b  = (const float*)d_in[15];
  const float* lnf_g = (const float*)d_in[16];
  const float* lnf_b = (const float*)d_in[17];

  char* ws = (char*)d_ws;
  size_t off = 0;
  auto alloc = [&](size_t bytes) {
    char* p = ws + off;
    off += (bytes + 255) & ~(size_t)255;
    return p;
  };
  bf16_t* wqT = (bf16_t*)alloc(6ull * 2304 * 768 * 2);
  bf16_t* waT = (bf16_t*)alloc(6ull * 768 * 768 * 2);
  bf16_t* wfT = (bf16_t*)alloc(6ull * 3072 * 768 * 2);
  bf16_t* woT = (bf16_t*)alloc(6ull * 768 * 3072 * 2);
  float*  h   = (float*) alloc(8192ull * 768 * 4);
  bf16_t* xb  = (bf16_t*)alloc(8192ull * 768 * 2);
  bf16_t* qkv = (bf16_t*)alloc(8192ull * 2304 * 2);
  bf16_t* abf = (bf16_t*)alloc(8192ull * 768 * 2);
  bf16_t* fb  = (bf16_t*)alloc(8192ull * 3072 * 2);
  if (off > ws_size) return;

  const dim3 tb(32, 8);
  for (int l = 0; l < 6; ++l) {
    transpose_cast<<<dim3(768 / 32, 2304 / 32), tb, 0, stream>>>(
        qkv_w + (long)l * 768 * 2304, wqT + (long)l * 2304 * 768, 768, 2304);
    transpose_cast<<<dim3(768 / 32, 768 / 32), tb, 0, stream>>>(
        ao_w + (long)l * 768 * 768, waT + (long)l * 768 * 768, 768, 768);
    transpose_cast<<<dim3(768 / 32, 3072 / 32), tb, 0, stream>>>(
        fc_w + (long)l * 768 * 3072, wfT + (long)l * 3072 * 768, 768, 3072);
    transpose_cast<<<dim3(3072 / 32, 768 / 32), tb, 0, stream>>>(
        op_w + (long)l * 3072 * 768, woT + (long)l * 768 * 3072, 3072, 768);
  }

  embed_kernel<<<24576, 256, 0, stream>>>(x_ids, wte, wpe, h);

  for (int l = 0; l < 6; ++l) {
    ln_kernel<true><<<8192, 256, 0, stream>>>(h, ln1_g + l * 768, ln1_b + l * 768, xb, nullptr);
    // qkv: 8192x2304, K=768 -> grid 32*9 = 288
    gemm256<2, 1><<<288, 512, 0, stream>>>(xb, wqT + (long)l * 2304 * 768,
                                           qkv_b + l * 2304, nullptr, qkv, 8192, 2304, 768);
    attn_kernel<<<768, 256, 0, stream>>>(qkv, mask, abf);
    // ao: 8192x768, K=768, split-2 -> grid 32*3*2 = 192 (atomic f32 += into h)
    gemm256<4, 2><<<192, 512, 0, stream>>>(abf, waT + (long)l * 768 * 768,
                                           ao_b + l * 768, h, nullptr, 8192, 768, 768);
    ln_kernel<true><<<8192, 256, 0, stream>>>(h, ln2_g + l * 768, ln2_b + l * 768, xb, nullptr);
    // fc: 8192x3072, K=768 -> grid 32*12 = 384
    gemm256<3, 1><<<384, 512, 0, stream>>>(xb, wfT + (long)l * 3072 * 768,
                                           fc_b + l * 3072, nullptr, fb, 8192, 3072, 768);
    // op: 8192x768, K=3072, split-2 -> grid 192 (atomic f32 += into h)
    gemm256<4, 2><<<192, 512, 0, stream>>>(fb, woT + (long)l * 768 * 3072,
                                           op_b + l * 768, h, nullptr, 8192, 768, 3072);
  }

  ln_kernel<false><<<8192, 256, 0, stream>>>(h, lnf_g, lnf_b, nullptr, (float*)d_out);
}

// Round 7
// 1851.550 us; speedup vs baseline: 1.2223x; 1.2223x over previous
//
#include <hip/hip_runtime.h>
#include <hip/hip_bf16.h>

typedef __bf16 bf16_t;
typedef __bf16 bf16x8 __attribute__((ext_vector_type(8)));
typedef float  f32x4  __attribute__((ext_vector_type(4)));

#define DEV __device__ __forceinline__

DEV void gload_lds16(const void* g, void* l) {
  __builtin_amdgcn_global_load_lds(
      (__attribute__((address_space(1))) void*)(void*)g,
      (__attribute__((address_space(3))) void*)l, 16, 0, 0);
}

// ---------------- weight transpose+cast: in fp32 [K][N] -> out bf16 [N][K]
__global__ __launch_bounds__(256)
void transpose_cast(const float* __restrict__ in, bf16_t* __restrict__ out,
                    int K, int N) {
  __shared__ float tile[32][33];
  const int k0 = blockIdx.x * 32;
  const int n0 = blockIdx.y * 32;
  const int tx = threadIdx.x;      // 0..31
  const int ty = threadIdx.y;      // 0..7
#pragma unroll
  for (int i = 0; i < 32; i += 8)
    tile[ty + i][tx] = in[(long)(k0 + ty + i) * N + n0 + tx];
  __syncthreads();
#pragma unroll
  for (int i = 0; i < 32; i += 8)
    out[(long)(n0 + ty + i) * K + k0 + tx] = (bf16_t)tile[tx][ty + i];
}

// ---------------- embedding: h = wte[ids] + wpe[s]
__global__ __launch_bounds__(256)
void embed_kernel(const int* __restrict__ ids, const float* __restrict__ wte,
                  const float* __restrict__ wpe, float* __restrict__ h) {
  const int idx = blockIdx.x * 256 + threadIdx.x;   // < 8192*768
  const int col = idx % 768;
  const int row = idx / 768;
  const int s   = row & 1023;
  h[idx] = wte[(long)ids[row] * 768 + col] + wpe[s * 768 + col];
}

// ---------------- layernorm, one block (256 thr) per row of 768
template <bool BF16OUT>
__global__ __launch_bounds__(256)
void ln_kernel(const float* __restrict__ x, const float* __restrict__ g,
               const float* __restrict__ b, bf16_t* __restrict__ ob,
               float* __restrict__ of) {
  const long row = blockIdx.x;
  const float* xr = x + row * 768;
  const int t = threadIdx.x;
  float v0 = xr[t], v1 = xr[t + 256], v2 = xr[t + 512];
  float s  = v0 + v1 + v2;
  float sq = v0 * v0 + v1 * v1 + v2 * v2;
#pragma unroll
  for (int o = 32; o; o >>= 1) { s += __shfl_down(s, o); sq += __shfl_down(sq, o); }
  __shared__ float red[8];
  const int w = t >> 6;
  if ((t & 63) == 0) { red[w] = s; red[4 + w] = sq; }
  __syncthreads();
  s  = red[0] + red[1] + red[2] + red[3];
  sq = red[4] + red[5] + red[6] + red[7];
  const float mean = s * (1.f / 768.f);
  const float rs = rsqrtf(sq * (1.f / 768.f) - mean * mean + 1e-5f);
  float vv[3] = {v0, v1, v2};
#pragma unroll
  for (int i = 0; i < 3; ++i) {
    const int col = t + i * 256;
    const float o2 = (vv[i] - mean) * rs * g[col] + b[col];
    if (BF16OUT) ob[row * 768 + col] = (bf16_t)o2;
    else         of[row * 768 + col] = o2;
  }
}

// ---------------- GEMM: C[M][N] = A[M][K](bf16) * Bt[N][K](bf16)^T + bias
// m97-class structure: BK=64, SINGLE-buffered LDS (32 KB/block -> 4 blocks/CU,
// co-resident blocks hide barrier drains), XOR-swizzled (0-conflict, proven),
// XCD-aware block swizzle, optional split-K via f32 atomics.
// EPI: 0 f32 store, 1 f32 +=, 2 bf16, 3 gelu->bf16, 4 atomicAdd f32 (split-K).
template <int EPI, int BN, int NSP>
__global__ __launch_bounds__(256, 4)
void gemm_bt(const bf16_t* __restrict__ A, const bf16_t* __restrict__ Bt,
             const float* __restrict__ bias, float* __restrict__ Cf,
             bf16_t* __restrict__ Cb, int M, int N, int K) {
  constexpr int NI = BN / 32;            // n-fragments per wave
  __shared__ bf16_t As[128 * 64];
  __shared__ bf16_t Bs[BN * 64];
  const int tid  = threadIdx.x;
  const int lane = tid & 63, w = tid >> 6;
  const int col = lane & 15, s16 = lane >> 4;
  const int nbn = N / BN;
  // XCD-aware swizzle (grids always %8==0 here)
  const int cpx = gridDim.x >> 3;
  const int swz = (blockIdx.x & 7) * cpx + (blockIdx.x >> 3);
  const int ksp = (NSP > 1) ? (swz % NSP) : 0;
  const int t0  = (NSP > 1) ? (swz / NSP) : swz;
  const int bm = t0 / nbn, bn = t0 % nbn;
  const int wr = w >> 1, wc = w & 1;
  const int Ksub = K / NSP;
  const long kofs = (long)ksp * Ksub;

  f32x4 acc[4][NI];
#pragma unroll
  for (int i = 0; i < 4; ++i)
#pragma unroll
    for (int j = 0; j < NI; ++j) acc[i][j] = f32x4{0.f, 0.f, 0.f, 0.f};

  const long arow0 = (long)bm * 128;
  const long brow0 = (long)bn * BN;

  auto stage = [&](int k0) {
#pragma unroll
    for (int i = 0; i < 4; ++i) {
      const int c = i * 256 + tid;
      const int row = c >> 3, slot = c & 7;
      gload_lds16(A + (arow0 + row) * (long)K + kofs + k0 + ((slot ^ (row & 7)) << 3),
                  (char*)As + c * 16);
    }
#pragma unroll
    for (int i = 0; i < BN / 32; ++i) {
      const int c = i * 256 + tid;
      const int row = c >> 3, slot = c & 7;
      gload_lds16(Bt + (brow0 + row) * (long)K + kofs + k0 + ((slot ^ (row & 7)) << 3),
                  (char*)Bs + c * 16);
    }
  };

  const int nt = Ksub >> 6;
  for (int t = 0; t < nt; ++t) {
    stage(t << 6);
    __syncthreads();        // drains vmcnt(0): tile staged

    bf16x8 af[2][4], bfr[2][NI];
#pragma unroll
    for (int mi = 0; mi < 4; ++mi) {
      const int row = wr * 64 + mi * 16 + col;
#pragma unroll
      for (int ks = 0; ks < 2; ++ks) {
        const int slot = ks * 4 + s16;
        af[ks][mi] = *(const bf16x8*)((char*)As + row * 128 +
                                      ((slot ^ (row & 7)) << 4));
      }
    }
#pragma unroll
    for (int ni = 0; ni < NI; ++ni) {
      const int row = wc * (BN / 2) + ni * 16 + col;
#pragma unroll
      for (int ks = 0; ks < 2; ++ks) {
        const int slot = ks * 4 + s16;
        bfr[ks][ni] = *(const bf16x8*)((char*)Bs + row * 128 +
                                       ((slot ^ (row & 7)) << 4));
      }
    }
#pragma unroll
    for (int ks = 0; ks < 2; ++ks)
#pragma unroll
      for (int mi = 0; mi < 4; ++mi)
#pragma unroll
        for (int ni = 0; ni < NI; ++ni)
          acc[mi][ni] = __builtin_amdgcn_mfma_f32_16x16x32_bf16(
              af[ks][mi], bfr[ks][ni], acc[mi][ni], 0, 0, 0);

    __syncthreads();        // all reads done before next stage overwrites
  }

  const int colb = bn * BN + wc * (BN / 2) + col;
  const int rowb = bm * 128 + wr * 64 + (s16 << 2);
#pragma unroll
  for (int ni = 0; ni < NI; ++ni) {
    const int ccol = colb + ni * 16;
    const float bv = (EPI == 4) ? (ksp == 0 ? bias[ccol] : 0.f) : bias[ccol];
#pragma unroll
    for (int mi = 0; mi < 4; ++mi) {
      const int row = rowb + mi * 16;
#pragma unroll
      for (int r = 0; r < 4; ++r) {
        const float v = acc[mi][ni][r] + bv;
        const long idx = (long)(row + r) * N + ccol;
        if (EPI == 0)      Cf[idx] = v;
        else if (EPI == 1) Cf[idx] += v;
        else if (EPI == 2) Cb[idx] = (bf16_t)v;
        else if (EPI == 3) {
          const float z = 0.7978845608028654f * (v + 0.044715f * v * v * v);
          Cb[idx] = (bf16_t)(v / (1.f + __expf(-2.f * z)));
        } else {
          atomicAdd(&Cf[idx], v);
        }
      }
    }
  }
}

// ---------------- flash attention: paired q-tiles, double-buffered K/V,
// async-stage split (issue-early/write-late), one barrier per kt-iteration.
__global__ __launch_bounds__(256, 3)
void attn_kernel(const bf16_t* __restrict__ qkv, const float* __restrict__ mask,
                 bf16_t* __restrict__ out) {
  __shared__ bf16_t Kl[2][64 * 64];   // [key][dh], slot-swizzled
  __shared__ bf16_t Vt[2][64 * 64];   // [d][k],   slot-swizzled
  __shared__ bf16_t Pl[4][16 * 64];   // per-wave [q][key], slot-swizzled
  const int tid = threadIdx.x, lane = tid & 63, w = tid >> 6;
  const int col = lane & 15, s16 = lane >> 4, l7 = lane & 7;
  const int qp = blockIdx.x & 7;      // pair id: handles qt = qp and 15-qp
  const int bh = blockIdx.x >> 3;     // 0..95
  const int b = bh / 12, h = bh % 12;
  const int sw0 = (s16 ^ l7) << 4;
  const int sw1 = ((s16 + 4) ^ l7) << 4;
  char* const plw = (char*)&Pl[w][0];
  const long qkvb = (long)b * 1024 * 2304;

  auto stageK = [&](int buf, int k0) {
#pragma unroll
    for (int i = 0; i < 2; ++i) {
      const int c = i * 256 + tid;
      const int krow = c >> 3, slot = c & 7;
      gload_lds16(qkv + qkvb + (long)(k0 + krow) * 2304 + 768 + h * 64 +
                      ((slot ^ (krow & 7)) << 3),
                  (char*)&Kl[buf][0] + i * 4096 + w * 1024);
    }
  };
  auto loadV = [&](int k0, bf16x8& t0, bf16x8& t1) {
    const bf16_t* vbase = qkv + qkvb + 1536 + h * 64;
#pragma unroll
    for (int i = 0; i < 2; ++i) {
      const int c = i * 256 + tid;
      const int d = c & 63, koct = c >> 6;
      const bf16_t* vsrc = vbase + (long)(k0 + koct * 8) * 2304 + d;
      bf16x8 tv;
#pragma unroll
      for (int j = 0; j < 8; ++j) tv[j] = vsrc[(long)j * 2304];
      if (i == 0) t0 = tv; else t1 = tv;
    }
  };
  auto storeV = [&](int buf, const bf16x8& t0, const bf16x8& t1) {
#pragma unroll
    for (int i = 0; i < 2; ++i) {
      const int c = i * 256 + tid;
      const int d = c & 63, koct = c >> 6;
      *(bf16x8*)((char*)&Vt[buf][0] + d * 128 + ((koct ^ (d & 7)) << 4)) =
          (i == 0) ? t0 : t1;
    }
  };

#pragma unroll 1
  for (int pass = 0; pass < 2; ++pass) {
    const int qt = pass ? (15 - qp) : qp;
    const int qrow0 = qt * 64 + w * 16;
    const long rowQ = (long)(b * 1024 + qrow0 + col) * 2304 + h * 64;
    const bf16x8 aq0 = *(const bf16x8*)&qkv[rowQ + s16 * 8];
    const bf16x8 aq1 = *(const bf16x8*)&qkv[rowQ + 32 + s16 * 8];
    const int qb = qrow0 + s16 * 4;
    const float* mrow = mask + ((long)b * 1024 + qb) * 1024;

    auto loadM = [&](int k0, float (&m)[4][4]) {
#pragma unroll
      for (int g = 0; g < 4; ++g)
#pragma unroll
        for (int r = 0; r < 4; ++r)
          m[g][r] = mrow[(long)r * 1024 + k0 + g * 16 + col];
    };

    float m_run[4], l_run[4];
    f32x4 o_acc[4];
#pragma unroll
    for (int r = 0; r < 4; ++r) { m_run[r] = -INFINITY; l_run[r] = 0.f; }
#pragma unroll
    for (int go = 0; go < 4; ++go) o_acc[go] = f32x4{0.f, 0.f, 0.f, 0.f};

    bf16x8 tv0, tv1;
    stageK(0, 0);
    loadV(0, tv0, tv1);
    storeV(0, tv0, tv1);
    float msk[4][4];
    loadM(0, msk);
    __syncthreads();

#pragma unroll 1
    for (int kt = 0; kt <= qt; ++kt) {
      const int cur = kt & 1;
      const bool more = kt < qt;
      const int k0 = kt * 64;
      float mnx[4][4];
      if (more) {
        stageK(cur ^ 1, k0 + 64);
        loadV(k0 + 64, tv0, tv1);
        loadM(k0 + 64, mnx);
      }

      f32x4 sf[4];
      __builtin_amdgcn_s_setprio(1);
#pragma unroll
      for (int g = 0; g < 4; ++g) {
        const int rbyte = (g * 16 + col) * 128;
        bf16x8 bk0 = *(const bf16x8*)((char*)&Kl[cur][0] + rbyte + sw0);
        bf16x8 bk1 = *(const bf16x8*)((char*)&Kl[cur][0] + rbyte + sw1);
        f32x4 z = f32x4{0.f, 0.f, 0.f, 0.f};
        z = __builtin_amdgcn_mfma_f32_16x16x32_bf16(aq0, bk0, z, 0, 0, 0);
        z = __builtin_amdgcn_mfma_f32_16x16x32_bf16(aq1, bk1, z, 0, 0, 0);
        sf[g] = z;
      }
      __builtin_amdgcn_s_setprio(0);

      const bool diag = (kt == qt);
      float sv[4][4];
#pragma unroll
      for (int g = 0; g < 4; ++g)
#pragma unroll
        for (int r = 0; r < 4; ++r) {
          float s = sf[g][r] * 0.125f + msk[g][r];
          if (diag && (k0 + g * 16 + col) > (qb + r)) s = -INFINITY;
          sv[g][r] = s;
        }
#pragma unroll
      for (int r = 0; r < 4; ++r) {
        float mx = fmaxf(fmaxf(sv[0][r], sv[1][r]), fmaxf(sv[2][r], sv[3][r]));
#pragma unroll
        for (int o = 8; o; o >>= 1) mx = fmaxf(mx, __shfl_xor(mx, o));
        const float m_new = fmaxf(m_run[r], mx);
        const float f = __expf(m_run[r] - m_new);
        m_run[r] = m_new;
        float sum = 0.f;
#pragma unroll
        for (int g = 0; g < 4; ++g) {
          const float p = __expf(sv[g][r] - m_new);
          sv[g][r] = p;
          sum += p;
        }
#pragma unroll
        for (int o = 8; o; o >>= 1) sum += __shfl_xor(sum, o);
        l_run[r] = l_run[r] * f + sum;
#pragma unroll
        for (int go = 0; go < 4; ++go) o_acc[go][r] *= f;
      }

#pragma unroll
      for (int g = 0; g < 4; ++g) {
        const int ks = 2 * g + (col >> 3);
#pragma unroll
        for (int r = 0; r < 4; ++r) {
          const int qr = s16 * 4 + r;
          *(bf16_t*)(plw + qr * 128 + ((ks ^ (qr & 7)) << 4) + l7 * 2) = (bf16_t)sv[g][r];
        }
      }
      const bf16x8 pa0 = *(const bf16x8*)(plw + col * 128 + sw0);
      const bf16x8 pa1 = *(const bf16x8*)(plw + col * 128 + sw1);
      __builtin_amdgcn_s_setprio(1);
#pragma unroll
      for (int go = 0; go < 4; ++go) {
        const int dbyte = (go * 16 + col) * 128;
        bf16x8 bv0 = *(const bf16x8*)((char*)&Vt[cur][0] + dbyte + sw0);
        bf16x8 bv1 = *(const bf16x8*)((char*)&Vt[cur][0] + dbyte + sw1);
        o_acc[go] = __builtin_amdgcn_mfma_f32_16x16x32_bf16(pa0, bv0, o_acc[go], 0, 0, 0);
        o_acc[go] = __builtin_amdgcn_mfma_f32_16x16x32_bf16(pa1, bv1, o_acc[go], 0, 0, 0);
      }
      __builtin_amdgcn_s_setprio(0);

      if (more) {
        storeV(cur ^ 1, tv0, tv1);
#pragma unroll
        for (int g = 0; g < 4; ++g)
#pragma unroll
          for (int r = 0; r < 4; ++r) msk[g][r] = mnx[g][r];
      }
      __syncthreads();
    }

    float inv[4];
#pragma unroll
    for (int r = 0; r < 4; ++r) inv[r] = 1.f / l_run[r];
#pragma unroll
    for (int go = 0; go < 4; ++go)
#pragma unroll
      for (int r = 0; r < 4; ++r)
        out[(long)(b * 1024 + qb + r) * 768 + h * 64 + go * 16 + col] =
            (bf16_t)(o_acc[go][r] * inv[r]);
  }
}

// ---------------- host
extern "C" void kernel_launch(void* const* d_in, const int* in_sizes, int n_in,
                              void* d_out, int out_size, void* d_ws, size_t ws_size,
                              hipStream_t stream) {
  const int*   x_ids = (const int*)d_in[0];
  const float* mask  = (const float*)d_in[1];
  const float* wte   = (const float*)d_in[2];
  const float* wpe   = (const float*)d_in[3];
  const float* ln1_g = (const float*)d_in[4];
  const float* ln1_b = (const float*)d_in[5];
  const float* qkv_w = (const float*)d_in[6];
  const float* qkv_b = (const float*)d_in[7];
  const float* ao_w  = (const float*)d_in[8];
  const float* ao_b  = (const float*)d_in[9];
  const float* ln2_g = (const float*)d_in[10];
  const float* ln2_b = (const float*)d_in[11];
  const float* fc_w  = (const float*)d_in[12];
  const float* fc_b  = (const float*)d_in[13];
  const float* op_w  = (const float*)d_in[14];
  const float* op_b  = (const float*)d_in[15];
  const float* lnf_g = (const float*)d_in[16];
  const float* lnf_b = (const float*)d_in[17];

  char* ws = (char*)d_ws;
  size_t off = 0;
  auto alloc = [&](size_t bytes) {
    char* p = ws + off;
    off += (bytes + 255) & ~(size_t)255;
    return p;
  };
  bf16_t* wqT = (bf16_t*)alloc(6ull * 2304 * 768 * 2);
  bf16_t* waT = (bf16_t*)alloc(6ull * 768 * 768 * 2);
  bf16_t* wfT = (bf16_t*)alloc(6ull * 3072 * 768 * 2);
  bf16_t* woT = (bf16_t*)alloc(6ull * 768 * 3072 * 2);
  float*  h   = (float*) alloc(8192ull * 768 * 4);
  bf16_t* xb  = (bf16_t*)alloc(8192ull * 768 * 2);
  bf16_t* qkv = (bf16_t*)alloc(8192ull * 2304 * 2);
  bf16_t* abf = (bf16_t*)alloc(8192ull * 768 * 2);
  bf16_t* fb  = (bf16_t*)alloc(8192ull * 3072 * 2);
  if (off > ws_size) return;

  const dim3 tb(32, 8);
  for (int l = 0; l < 6; ++l) {
    transpose_cast<<<dim3(768 / 32, 2304 / 32), tb, 0, stream>>>(
        qkv_w + (long)l * 768 * 2304, wqT + (long)l * 2304 * 768, 768, 2304);
    transpose_cast<<<dim3(768 / 32, 768 / 32), tb, 0, stream>>>(
        ao_w + (long)l * 768 * 768, waT + (long)l * 768 * 768, 768, 768);
    transpose_cast<<<dim3(768 / 32, 3072 / 32), tb, 0, stream>>>(
        fc_w + (long)l * 768 * 3072, wfT + (long)l * 3072 * 768, 768, 3072);
    transpose_cast<<<dim3(3072 / 32, 768 / 32), tb, 0, stream>>>(
        op_w + (long)l * 3072 * 768, woT + (long)l * 768 * 3072, 3072, 768);
  }

  embed_kernel<<<24576, 256, 0, stream>>>(x_ids, wte, wpe, h);

  for (int l = 0; l < 6; ++l) {
    ln_kernel<true><<<8192, 256, 0, stream>>>(h, ln1_g + l * 768, ln1_b + l * 768, xb, nullptr);
    // qkv: 8192x2304 K=768 -> grid 64*18 = 1152
    gemm_bt<2, 128, 1><<<1152, 256, 0, stream>>>(xb, wqT + (long)l * 2304 * 768,
                                                 qkv_b + l * 2304, nullptr, qkv, 8192, 2304, 768);
    attn_kernel<<<768, 256, 0, stream>>>(qkv, mask, abf);
    // ao: 8192x768 K=768 split-2 -> grid 64*6*2 = 768 (atomic += into h)
    gemm_bt<4, 128, 2><<<768, 256, 0, stream>>>(abf, waT + (long)l * 768 * 768,
                                                ao_b + l * 768, h, nullptr, 8192, 768, 768);
    ln_kernel<true><<<8192, 256, 0, stream>>>(h, ln2_g + l * 768, ln2_b + l * 768, xb, nullptr);
    // fc: 8192x3072 K=768 -> grid 64*24 = 1536
    gemm_bt<3, 128, 1><<<1536, 256, 0, stream>>>(xb, wfT + (long)l * 3072 * 768,
                                                 fc_b + l * 3072, nullptr, fb, 8192, 3072, 768);
    // op: 8192x768 K=3072 split-2 -> grid 768 (atomic += into h)
    gemm_bt<4, 128, 2><<<768, 256, 0, stream>>>(fb, woT + (long)l * 768 * 3072,
                                                op_b + l * 768, h, nullptr, 8192, 768, 3072);
  }

  ln_kernel<false><<<8192, 256, 0, stream>>>(h, lnf_g, lnf_b, nullptr, (float*)d_out);
}

// Round 8
// 1738.274 us; speedup vs baseline: 1.3020x; 1.0652x over previous
//
#include <hip/hip_runtime.h>
#include <hip/hip_bf16.h>

typedef __bf16 bf16_t;
typedef __bf16 bf16x8 __attribute__((ext_vector_type(8)));
typedef float  f32x4  __attribute__((ext_vector_type(4)));

#define DEV __device__ __forceinline__

DEV void gload_lds16(const void* g, void* l) {
  __builtin_amdgcn_global_load_lds(
      (__attribute__((address_space(1))) void*)(void*)g,
      (__attribute__((address_space(3))) void*)l, 16, 0, 0);
}

// ---------------- weight transpose+cast: in fp32 [K][N] -> out bf16 [N][K]
__global__ __launch_bounds__(256)
void transpose_cast(const float* __restrict__ in, bf16_t* __restrict__ out,
                    int K, int N) {
  __shared__ float tile[32][33];
  const int k0 = blockIdx.x * 32;
  const int n0 = blockIdx.y * 32;
  const int tx = threadIdx.x;      // 0..31
  const int ty = threadIdx.y;      // 0..7
#pragma unroll
  for (int i = 0; i < 32; i += 8)
    tile[ty + i][tx] = in[(long)(k0 + ty + i) * N + n0 + tx];
  __syncthreads();
#pragma unroll
  for (int i = 0; i < 32; i += 8)
    out[(long)(n0 + ty + i) * K + k0 + tx] = (bf16_t)tile[tx][ty + i];
}

// ---------------- embedding: h = wte[ids] + wpe[s]
__global__ __launch_bounds__(256)
void embed_kernel(const int* __restrict__ ids, const float* __restrict__ wte,
                  const float* __restrict__ wpe, float* __restrict__ h) {
  const int idx = blockIdx.x * 256 + threadIdx.x;   // < 8192*768
  const int col = idx % 768;
  const int row = idx / 768;
  const int s   = row & 1023;
  h[idx] = wte[(long)ids[row] * 768 + col] + wpe[s * 768 + col];
}

// ---------------- layernorm, one block (256 thr) per row of 768
template <bool BF16OUT>
__global__ __launch_bounds__(256)
void ln_kernel(const float* __restrict__ x, const float* __restrict__ g,
               const float* __restrict__ b, bf16_t* __restrict__ ob,
               float* __restrict__ of) {
  const long row = blockIdx.x;
  const float* xr = x + row * 768;
  const int t = threadIdx.x;
  float v0 = xr[t], v1 = xr[t + 256], v2 = xr[t + 512];
  float s  = v0 + v1 + v2;
  float sq = v0 * v0 + v1 * v1 + v2 * v2;
#pragma unroll
  for (int o = 32; o; o >>= 1) { s += __shfl_down(s, o); sq += __shfl_down(sq, o); }
  __shared__ float red[8];
  const int w = t >> 6;
  if ((t & 63) == 0) { red[w] = s; red[4 + w] = sq; }
  __syncthreads();
  s  = red[0] + red[1] + red[2] + red[3];
  sq = red[4] + red[5] + red[6] + red[7];
  const float mean = s * (1.f / 768.f);
  const float rs = rsqrtf(sq * (1.f / 768.f) - mean * mean + 1e-5f);
  float vv[3] = {v0, v1, v2};
#pragma unroll
  for (int i = 0; i < 3; ++i) {
    const int col = t + i * 256;
    const float o2 = (vv[i] - mean) * rs * g[col] + b[col];
    if (BF16OUT) ob[row * 768 + col] = (bf16_t)o2;
    else         of[row * 768 + col] = o2;
  }
}

// ---------------- narrow GEMM (ao/op): BM=128, BN=64, BK=64, 256 thr,
// single-buffered 24 KB LDS, XOR-swizzle, XCD swizzle. EPI as below.
template <int EPI, int BN>
__global__ __launch_bounds__(256, 4)
void gemm_bt(const bf16_t* __restrict__ A, const bf16_t* __restrict__ Bt,
             const float* __restrict__ bias, float* __restrict__ Cf,
             bf16_t* __restrict__ Cb, int M, int N, int K) {
  constexpr int NI = BN / 32;            // n-fragments per wave
  __shared__ bf16_t As[128 * 64];
  __shared__ bf16_t Bs[BN * 64];
  const int tid  = threadIdx.x;
  const int lane = tid & 63, w = tid >> 6;
  const int col = lane & 15, s16 = lane >> 4;
  const int nbn = N / BN;
  const int cpx = gridDim.x >> 3;
  const int bid = (blockIdx.x & 7) * cpx + (blockIdx.x >> 3);
  const int bm = bid / nbn, bn = bid % nbn;
  const int wr = w >> 1, wc = w & 1;

  f32x4 acc[4][NI];
#pragma unroll
  for (int i = 0; i < 4; ++i)
#pragma unroll
    for (int j = 0; j < NI; ++j) acc[i][j] = f32x4{0.f, 0.f, 0.f, 0.f};

  const long arow0 = (long)bm * 128;
  const long brow0 = (long)bn * BN;

  const int nt = K >> 6;
  for (int t = 0; t < nt; ++t) {
    const int k0 = t << 6;
#pragma unroll
    for (int i = 0; i < 4; ++i) {
      const int c = i * 256 + tid;
      const int row = c >> 3, slot = c & 7;
      gload_lds16(A + (arow0 + row) * (long)K + k0 + ((slot ^ (row & 7)) << 3),
                  (char*)As + c * 16);
    }
#pragma unroll
    for (int i = 0; i < BN / 32; ++i) {
      const int c = i * 256 + tid;
      const int row = c >> 3, slot = c & 7;
      gload_lds16(Bt + (brow0 + row) * (long)K + k0 + ((slot ^ (row & 7)) << 3),
                  (char*)Bs + c * 16);
    }
    __syncthreads();        // drains vmcnt(0): tile staged

    bf16x8 af[2][4], bfr[2][NI];
#pragma unroll
    for (int mi = 0; mi < 4; ++mi) {
      const int row = wr * 64 + mi * 16 + col;
#pragma unroll
      for (int ks = 0; ks < 2; ++ks) {
        const int slot = ks * 4 + s16;
        af[ks][mi] = *(const bf16x8*)((char*)As + row * 128 +
                                      ((slot ^ (row & 7)) << 4));
      }
    }
#pragma unroll
    for (int ni = 0; ni < NI; ++ni) {
      const int row = wc * (BN / 2) + ni * 16 + col;
#pragma unroll
      for (int ks = 0; ks < 2; ++ks) {
        const int slot = ks * 4 + s16;
        bfr[ks][ni] = *(const bf16x8*)((char*)Bs + row * 128 +
                                       ((slot ^ (row & 7)) << 4));
      }
    }
#pragma unroll
    for (int ks = 0; ks < 2; ++ks)
#pragma unroll
      for (int mi = 0; mi < 4; ++mi)
#pragma unroll
        for (int ni = 0; ni < NI; ++ni)
          acc[mi][ni] = __builtin_amdgcn_mfma_f32_16x16x32_bf16(
              af[ks][mi], bfr[ks][ni], acc[mi][ni], 0, 0, 0);

    __syncthreads();        // all reads done before next stage overwrites
  }

  const int colb = bn * BN + wc * (BN / 2) + col;
  const int rowb = bm * 128 + wr * 64 + (s16 << 2);
#pragma unroll
  for (int ni = 0; ni < NI; ++ni) {
    const int ccol = colb + ni * 16;
    const float bv = bias[ccol];
#pragma unroll
    for (int mi = 0; mi < 4; ++mi) {
      const int row = rowb + mi * 16;
#pragma unroll
      for (int r = 0; r < 4; ++r) {
        const float v = acc[mi][ni][r] + bv;
        const long idx = (long)(row + r) * N + ccol;
        if (EPI == 0)      Cf[idx] = v;
        else if (EPI == 1) Cf[idx] += v;
        else if (EPI == 2) Cb[idx] = (bf16_t)v;
        else {
          const float z = 0.7978845608028654f * (v + 0.044715f * v * v * v);
          Cb[idx] = (bf16_t)(v / (1.f + __expf(-2.f * z)));
        }
      }
    }
  }
}

// ---------------- wide GEMM (qkv/fc): BM=128, BN=256, BK=64, 512 thr =
// 8 waves (2M x 4N), single-buffered 48 KB LDS (2 blocks/CU), XOR-swizzle,
// XCD swizzle. 85 FLOP/staged-byte (1.33x the 128^2 tile), half the barrier
// events per FLOP. EPI: 2 bf16 store, 3 gelu->bf16.
template <int EPI>
__global__ __launch_bounds__(512, 4)
void gemm_wide(const bf16_t* __restrict__ A, const bf16_t* __restrict__ Bt,
               const float* __restrict__ bias, float* __restrict__ Cf,
               bf16_t* __restrict__ Cb, int M, int N, int K) {
  __shared__ bf16_t As[128 * 64];   // 16 KB
  __shared__ bf16_t Bs[256 * 64];   // 32 KB
  const int tid = threadIdx.x;
  const int lane = tid & 63, w = tid >> 6;
  const int col = lane & 15, s16 = lane >> 4;
  const int wm = w >> 2, wn = w & 3;        // 2 x 4 waves, 64x64 out each
  const int nbn = N >> 8;
  const int cpx = gridDim.x >> 3;
  const int bid = (blockIdx.x & 7) * cpx + (blockIdx.x >> 3);
  const int bm = bid / nbn, bn = bid % nbn;
  const long arow0 = (long)bm * 128, brow0 = (long)bn * 256;

  f32x4 acc[4][4];
#pragma unroll
  for (int i = 0; i < 4; ++i)
#pragma unroll
    for (int j = 0; j < 4; ++j) acc[i][j] = f32x4{0.f, 0.f, 0.f, 0.f};

  const int nt = K >> 6;
  for (int t = 0; t < nt; ++t) {
    const int k0 = t << 6;
#pragma unroll
    for (int i = 0; i < 2; ++i) {           // A: 128 rows = 1024 slots
      const int c = i * 512 + tid;
      const int row = c >> 3, slot = c & 7;
      gload_lds16(A + (arow0 + row) * (long)K + k0 + ((slot ^ (row & 7)) << 3),
                  (char*)As + c * 16);
    }
#pragma unroll
    for (int i = 0; i < 4; ++i) {           // B: 256 rows = 2048 slots
      const int c = i * 512 + tid;
      const int row = c >> 3, slot = c & 7;
      gload_lds16(Bt + (brow0 + row) * (long)K + k0 + ((slot ^ (row & 7)) << 3),
                  (char*)Bs + c * 16);
    }
    __syncthreads();        // drains vmcnt(0): tile staged

    bf16x8 af[2][4], bfr[2][4];
#pragma unroll
    for (int mi = 0; mi < 4; ++mi) {
      const int row = wm * 64 + mi * 16 + col;
#pragma unroll
      for (int ks = 0; ks < 2; ++ks) {
        const int slot = ks * 4 + s16;
        af[ks][mi] = *(const bf16x8*)((char*)As + row * 128 +
                                      ((slot ^ (row & 7)) << 4));
      }
    }
#pragma unroll
    for (int ni = 0; ni < 4; ++ni) {
      const int row = wn * 64 + ni * 16 + col;
#pragma unroll
      for (int ks = 0; ks < 2; ++ks) {
        const int slot = ks * 4 + s16;
        bfr[ks][ni] = *(const bf16x8*)((char*)Bs + row * 128 +
                                       ((slot ^ (row & 7)) << 4));
      }
    }
#pragma unroll
    for (int ks = 0; ks < 2; ++ks)
#pragma unroll
      for (int mi = 0; mi < 4; ++mi)
#pragma unroll
        for (int ni = 0; ni < 4; ++ni)
          acc[mi][ni] = __builtin_amdgcn_mfma_f32_16x16x32_bf16(
              af[ks][mi], bfr[ks][ni], acc[mi][ni], 0, 0, 0);

    __syncthreads();
  }

  const int rowb = bm * 128 + wm * 64 + (s16 << 2);
  const int colb = bn * 256 + wn * 64 + col;
#pragma unroll
  for (int ni = 0; ni < 4; ++ni) {
    const int ccol = colb + ni * 16;
    const float bv = bias[ccol];
#pragma unroll
    for (int mi = 0; mi < 4; ++mi) {
      const int row = rowb + mi * 16;
#pragma unroll
      for (int r = 0; r < 4; ++r) {
        const float v = acc[mi][ni][r] + bv;
        const long idx = (long)(row + r) * N + ccol;
        if (EPI == 2) Cb[idx] = (bf16_t)v;
        else {
          const float z = 0.7978845608028654f * (v + 0.044715f * v * v * v);
          Cb[idx] = (bf16_t)(v / (1.f + __expf(-2.f * z)));
        }
      }
    }
  }
}

// ---------------- flash attention: paired q-tiles, double-buffered K/V,
// async-stage split (issue-early/write-late), one barrier per kt-iteration.
__global__ __launch_bounds__(256, 3)
void attn_kernel(const bf16_t* __restrict__ qkv, const float* __restrict__ mask,
                 bf16_t* __restrict__ out) {
  __shared__ bf16_t Kl[2][64 * 64];   // [key][dh], slot-swizzled
  __shared__ bf16_t Vt[2][64 * 64];   // [d][k],   slot-swizzled
  __shared__ bf16_t Pl[4][16 * 64];   // per-wave [q][key], slot-swizzled
  const int tid = threadIdx.x, lane = tid & 63, w = tid >> 6;
  const int col = lane & 15, s16 = lane >> 4, l7 = lane & 7;
  const int qp = blockIdx.x & 7;      // pair id: handles qt = qp and 15-qp
  const int bh = blockIdx.x >> 3;     // 0..95
  const int b = bh / 12, h = bh % 12;
  const int sw0 = (s16 ^ l7) << 4;
  const int sw1 = ((s16 + 4) ^ l7) << 4;
  char* const plw = (char*)&Pl[w][0];
  const long qkvb = (long)b * 1024 * 2304;

  auto stageK = [&](int buf, int k0) {
#pragma unroll
    for (int i = 0; i < 2; ++i) {
      const int c = i * 256 + tid;
      const int krow = c >> 3, slot = c & 7;
      gload_lds16(qkv + qkvb + (long)(k0 + krow) * 2304 + 768 + h * 64 +
                      ((slot ^ (krow & 7)) << 3),
                  (char*)&Kl[buf][0] + i * 4096 + w * 1024);
    }
  };
  auto loadV = [&](int k0, bf16x8& t0, bf16x8& t1) {
    const bf16_t* vbase = qkv + qkvb + 1536 + h * 64;
#pragma unroll
    for (int i = 0; i < 2; ++i) {
      const int c = i * 256 + tid;
      const int d = c & 63, koct = c >> 6;
      const bf16_t* vsrc = vbase + (long)(k0 + koct * 8) * 2304 + d;
      bf16x8 tv;
#pragma unroll
      for (int j = 0; j < 8; ++j) tv[j] = vsrc[(long)j * 2304];
      if (i == 0) t0 = tv; else t1 = tv;
    }
  };
  auto storeV = [&](int buf, const bf16x8& t0, const bf16x8& t1) {
#pragma unroll
    for (int i = 0; i < 2; ++i) {
      const int c = i * 256 + tid;
      const int d = c & 63, koct = c >> 6;
      *(bf16x8*)((char*)&Vt[buf][0] + d * 128 + ((koct ^ (d & 7)) << 4)) =
          (i == 0) ? t0 : t1;
    }
  };

#pragma unroll 1
  for (int pass = 0; pass < 2; ++pass) {
    const int qt = pass ? (15 - qp) : qp;
    const int qrow0 = qt * 64 + w * 16;
    const long rowQ = (long)(b * 1024 + qrow0 + col) * 2304 + h * 64;
    const bf16x8 aq0 = *(const bf16x8*)&qkv[rowQ + s16 * 8];
    const bf16x8 aq1 = *(const bf16x8*)&qkv[rowQ + 32 + s16 * 8];
    const int qb = qrow0 + s16 * 4;
    const float* mrow = mask + ((long)b * 1024 + qb) * 1024;

    auto loadM = [&](int k0, float (&m)[4][4]) {
#pragma unroll
      for (int g = 0; g < 4; ++g)
#pragma unroll
        for (int r = 0; r < 4; ++r)
          m[g][r] = mrow[(long)r * 1024 + k0 + g * 16 + col];
    };

    float m_run[4], l_run[4];
    f32x4 o_acc[4];
#pragma unroll
    for (int r = 0; r < 4; ++r) { m_run[r] = -INFINITY; l_run[r] = 0.f; }
#pragma unroll
    for (int go = 0; go < 4; ++go) o_acc[go] = f32x4{0.f, 0.f, 0.f, 0.f};

    bf16x8 tv0, tv1;
    stageK(0, 0);
    loadV(0, tv0, tv1);
    storeV(0, tv0, tv1);
    float msk[4][4];
    loadM(0, msk);
    __syncthreads();

#pragma unroll 1
    for (int kt = 0; kt <= qt; ++kt) {
      const int cur = kt & 1;
      const bool more = kt < qt;
      const int k0 = kt * 64;
      float mnx[4][4];
      if (more) {
        stageK(cur ^ 1, k0 + 64);
        loadV(k0 + 64, tv0, tv1);
        loadM(k0 + 64, mnx);
      }

      f32x4 sf[4];
      __builtin_amdgcn_s_setprio(1);
#pragma unroll
      for (int g = 0; g < 4; ++g) {
        const int rbyte = (g * 16 + col) * 128;
        bf16x8 bk0 = *(const bf16x8*)((char*)&Kl[cur][0] + rbyte + sw0);
        bf16x8 bk1 = *(const bf16x8*)((char*)&Kl[cur][0] + rbyte + sw1);
        f32x4 z = f32x4{0.f, 0.f, 0.f, 0.f};
        z = __builtin_amdgcn_mfma_f32_16x16x32_bf16(aq0, bk0, z, 0, 0, 0);
        z = __builtin_amdgcn_mfma_f32_16x16x32_bf16(aq1, bk1, z, 0, 0, 0);
        sf[g] = z;
      }
      __builtin_amdgcn_s_setprio(0);

      const bool diag = (kt == qt);
      float sv[4][4];
#pragma unroll
      for (int g = 0; g < 4; ++g)
#pragma unroll
        for (int r = 0; r < 4; ++r) {
          float s = sf[g][r] * 0.125f + msk[g][r];
          if (diag && (k0 + g * 16 + col) > (qb + r)) s = -INFINITY;
          sv[g][r] = s;
        }
#pragma unroll
      for (int r = 0; r < 4; ++r) {
        float mx = fmaxf(fmaxf(sv[0][r], sv[1][r]), fmaxf(sv[2][r], sv[3][r]));
#pragma unroll
        for (int o = 8; o; o >>= 1) mx = fmaxf(mx, __shfl_xor(mx, o));
        const float m_new = fmaxf(m_run[r], mx);
        const float f = __expf(m_run[r] - m_new);
        m_run[r] = m_new;
        float sum = 0.f;
#pragma unroll
        for (int g = 0; g < 4; ++g) {
          const float p = __expf(sv[g][r] - m_new);
          sv[g][r] = p;
          sum += p;
        }
#pragma unroll
        for (int o = 8; o; o >>= 1) sum += __shfl_xor(sum, o);
        l_run[r] = l_run[r] * f + sum;
#pragma unroll
        for (int go = 0; go < 4; ++go) o_acc[go][r] *= f;
      }

#pragma unroll
      for (int g = 0; g < 4; ++g) {
        const int ks = 2 * g + (col >> 3);
#pragma unroll
        for (int r = 0; r < 4; ++r) {
          const int qr = s16 * 4 + r;
          *(bf16_t*)(plw + qr * 128 + ((ks ^ (qr & 7)) << 4) + l7 * 2) = (bf16_t)sv[g][r];
        }
      }
      const bf16x8 pa0 = *(const bf16x8*)(plw + col * 128 + sw0);
      const bf16x8 pa1 = *(const bf16x8*)(plw + col * 128 + sw1);
      __builtin_amdgcn_s_setprio(1);
#pragma unroll
      for (int go = 0; go < 4; ++go) {
        const int dbyte = (go * 16 + col) * 128;
        bf16x8 bv0 = *(const bf16x8*)((char*)&Vt[cur][0] + dbyte + sw0);
        bf16x8 bv1 = *(const bf16x8*)((char*)&Vt[cur][0] + dbyte + sw1);
        o_acc[go] = __builtin_amdgcn_mfma_f32_16x16x32_bf16(pa0, bv0, o_acc[go], 0, 0, 0);
        o_acc[go] = __builtin_amdgcn_mfma_f32_16x16x32_bf16(pa1, bv1, o_acc[go], 0, 0, 0);
      }
      __builtin_amdgcn_s_setprio(0);

      if (more) {
        storeV(cur ^ 1, tv0, tv1);
#pragma unroll
        for (int g = 0; g < 4; ++g)
#pragma unroll
          for (int r = 0; r < 4; ++r) msk[g][r] = mnx[g][r];
      }
      __syncthreads();
    }

    float inv[4];
#pragma unroll
    for (int r = 0; r < 4; ++r) inv[r] = 1.f / l_run[r];
#pragma unroll
    for (int go = 0; go < 4; ++go)
#pragma unroll
      for (int r = 0; r < 4; ++r)
        out[(long)(b * 1024 + qb + r) * 768 + h * 64 + go * 16 + col] =
            (bf16_t)(o_acc[go][r] * inv[r]);
  }
}

// ---------------- host
extern "C" void kernel_launch(void* const* d_in, const int* in_sizes, int n_in,
                              void* d_out, int out_size, void* d_ws, size_t ws_size,
                              hipStream_t stream) {
  const int*   x_ids = (const int*)d_in[0];
  const float* mask  = (const float*)d_in[1];
  const float* wte   = (const float*)d_in[2];
  const float* wpe   = (const float*)d_in[3];
  const float* ln1_g = (const float*)d_in[4];
  const float* ln1_b = (const float*)d_in[5];
  const float* qkv_w = (const float*)d_in[6];
  const float* qkv_b = (const float*)d_in[7];
  const float* ao_w  = (const float*)d_in[8];
  const float* ao_b  = (const float*)d_in[9];
  const float* ln2_g = (const float*)d_in[10];
  const float* ln2_b = (const float*)d_in[11];
  const float* fc_w  = (const float*)d_in[12];
  const float* fc_b  = (const float*)d_in[13];
  const float* op_w  = (const float*)d_in[14];
  const float* op_b  = (const float*)d_in[15];
  const float* lnf_g = (const float*)d_in[16];
  const float* lnf_b = (const float*)d_in[17];

  char* ws = (char*)d_ws;
  size_t off = 0;
  auto alloc = [&](size_t bytes) {
    char* p = ws + off;
    off += (bytes + 255) & ~(size_t)255;
    return p;
  };
  bf16_t* wqT = (bf16_t*)alloc(6ull * 2304 * 768 * 2);
  bf16_t* waT = (bf16_t*)alloc(6ull * 768 * 768 * 2);
  bf16_t* wfT = (bf16_t*)alloc(6ull * 3072 * 768 * 2);
  bf16_t* woT = (bf16_t*)alloc(6ull * 768 * 3072 * 2);
  float*  h   = (float*) alloc(8192ull * 768 * 4);
  bf16_t* xb  = (bf16_t*)alloc(8192ull * 768 * 2);
  bf16_t* qkv = (bf16_t*)alloc(8192ull * 2304 * 2);
  bf16_t* abf = (bf16_t*)alloc(8192ull * 768 * 2);
  bf16_t* fb  = (bf16_t*)alloc(8192ull * 3072 * 2);
  if (off > ws_size) return;

  const dim3 tb(32, 8);
  for (int l = 0; l < 6; ++l) {
    transpose_cast<<<dim3(768 / 32, 2304 / 32), tb, 0, stream>>>(
        qkv_w + (long)l * 768 * 2304, wqT + (long)l * 2304 * 768, 768, 2304);
    transpose_cast<<<dim3(768 / 32, 768 / 32), tb, 0, stream>>>(
        ao_w + (long)l * 768 * 768, waT + (long)l * 768 * 768, 768, 768);
    transpose_cast<<<dim3(768 / 32, 3072 / 32), tb, 0, stream>>>(
        fc_w + (long)l * 768 * 3072, wfT + (long)l * 3072 * 768, 768, 3072);
    transpose_cast<<<dim3(3072 / 32, 768 / 32), tb, 0, stream>>>(
        op_w + (long)l * 3072 * 768, woT + (long)l * 768 * 3072, 3072, 768);
  }

  embed_kernel<<<24576, 256, 0, stream>>>(x_ids, wte, wpe, h);

  for (int l = 0; l < 6; ++l) {
    ln_kernel<true><<<8192, 256, 0, stream>>>(h, ln1_g + l * 768, ln1_b + l * 768, xb, nullptr);
    // qkv: 8192x2304 K=768 -> wide grid 64*9 = 576
    gemm_wide<2><<<576, 512, 0, stream>>>(xb, wqT + (long)l * 2304 * 768,
                                          qkv_b + l * 2304, nullptr, qkv, 8192, 2304, 768);
    attn_kernel<<<768, 256, 0, stream>>>(qkv, mask, abf);
    // ao: 8192x768 K=768 -> narrow grid 64*12 = 768, residual +=
    gemm_bt<1, 64><<<768, 256, 0, stream>>>(abf, waT + (long)l * 768 * 768,
                                            ao_b + l * 768, h, nullptr, 8192, 768, 768);
    ln_kernel<true><<<8192, 256, 0, stream>>>(h, ln2_g + l * 768, ln2_b + l * 768, xb, nullptr);
    // fc: 8192x3072 K=768 -> wide grid 64*12 = 768
    gemm_wide<3><<<768, 512, 0, stream>>>(xb, wfT + (long)l * 3072 * 768,
                                          fc_b + l * 3072, nullptr, fb, 8192, 3072, 768);
    // op: 8192x768 K=3072 -> narrow grid 768, residual +=
    gemm_bt<1, 64><<<768, 256, 0, stream>>>(fb, woT + (long)l * 768 * 3072,
                                            op_b + l * 768, h, nullptr, 8192, 768, 3072);
  }

  ln_kernel<false><<<8192, 256, 0, stream>>>(h, lnf_g, lnf_b, nullptr, (float*)d_out);
}